// Round 7
// baseline (256.215 us; speedup 1.0000x reference)
//
#include <hip/hip_runtime.h>
#include <cstdint>
#include <cstddef>

// Asymm_3d_spconv: ResContextBlock + ReconBlock over submanifold sparse convs.
// Round 7: kill the 2.24x write amplification (86MB vs 38.4MB actual) from
// scattered 2-byte hi/lo stores. Intermediate rows now interleave hi/lo per
// channel as one uint32 (h | l<<16): epilogue stores one packed dword/elem ->
// 64B sectors fully covered, no RMW, no LDS transpose. Weights prepped to the
// interleaved K-space: per 16-ch chunk, term0 = [wh,wh] (duplicated), term1 =
// [wl,0]; AI.B0 + AI.B1 = (h+l)wh + h*wl = same 3-term hi/lo product as
// rounds 5/6 (error ~2^-18). +33% MFMAs on CIN32 stages (util 7% -> ~10%,
// free). Also: add_y folded into c3's epilogue (addsrc), detect/canon_weights
// dispatches replaced by inline per-wave dtype probe + one prep_all kernel,
// recon gathers the shared center tap once for all 3 groups. 6 dispatches.

#define SLOPE 0.01f
#define BN_EPS 1e-5f

typedef __attribute__((ext_vector_type(8))) short bf16x8;
typedef __attribute__((ext_vector_type(4))) float f32x4;

__device__ __forceinline__ float bflo(uint32_t w) {
    union { uint32_t i; float f; } v; v.i = w << 16; return v.f;
}
__device__ __forceinline__ float bfhi(uint32_t w) {
    union { uint32_t i; float f; } v; v.i = w & 0xffff0000u; return v.f;
}
__device__ __forceinline__ float bf2f(uint16_t u) {
    union { uint32_t i; float f; } v; v.i = ((uint32_t)u) << 16; return v.f;
}
__device__ __forceinline__ uint16_t f2bf(float f) {  // RNE
    union { float f; uint32_t i; } v; v.f = f;
    uint32_t x = v.i;
    return (uint16_t)((x + 0x7fffu + ((x >> 16) & 1u)) >> 16);
}

struct Taps9 { int t[9]; };
struct WSrcs { const void* p[8]; };  // W1,W12,W2,W3,Wr1,Wr2,Wr3,bnp

// Wf (prepped weights) short offsets. CIN16 stages: [t9][T2][co32][k32];
// CIN32 stages: [t9][G2][T2][co32][k32].
#define WF2_S0  0
#define WF2_S1  18432
#define WF2_S2  55296
#define WF2_S3  73728
#define WF2_S4  110592
#define WF2_END 147456
#define BN_CNT  896

// Inline dtype probe: sample 128 fixed even shorts of x. fp32 payload's low
// mantissa halves decode to huge/NaN bf16 with p~0.5 each -> miss prob 1e-38.
__device__ __forceinline__ int detect_f32_inline(const uint16_t* x16)
{
    int lane = threadIdx.x & 63;
    float a = bf2f(x16[4 * lane]);
    float b = bf2f(x16[4 * lane + 2]);
    int bad = (!(a > -16.f && a < 16.f)) || (!(b > -16.f && b < 16.f));
    return __ballot(bad) != 0ull;
}

__device__ __forceinline__ float readw(const void* p, int j, int f32)
{
    return f32 ? ((const float*)p)[j] : bf2f(((const uint16_t*)p)[j]);
}

// ---------------------------------------------------------------------------
// prep_all: Wf (all 5 stages, interleaved-K hi/lo B-frags; stage 4 folds the
// recon BN scale) + canonical fp32 bn table (7*128).
// ---------------------------------------------------------------------------
__global__ void prep_all(const uint16_t* __restrict__ xprobe, WSrcs srcs,
                         uint16_t* __restrict__ Wf, float* __restrict__ bnf)
{
    int f32 = detect_f32_inline(xprobe);
    int i = blockIdx.x * 256 + threadIdx.x;
    if (i < WF2_END) {
        int s, off;
        if      (i < WF2_S1) { s = 0; off = WF2_S0; }
        else if (i < WF2_S2) { s = 1; off = WF2_S1; }
        else if (i < WF2_S3) { s = 2; off = WF2_S2; }
        else if (i < WF2_S4) { s = 3; off = WF2_S3; }
        else                 { s = 4; off = WF2_S4; }
        int r = i - off;
        float w; int p, isdup;
        if (s == 0 || s == 2) {
            int t = r >> 11, T = (r >> 10) & 1;
            int co = (r >> 5) & 31, k = r & 31;
            int c = k >> 1; p = k & 1; isdup = (T == 0);
            w = readw(srcs.p[s == 0 ? 0 : 2], (t * 16 + c) * 32 + co, f32);
        } else {
            int t = r >> 12, r2 = r & 4095;
            int G = r2 >> 11, T = (r2 >> 10) & 1;
            int co = (r2 >> 5) & 31, k = r2 & 31;
            int c = G * 16 + (k >> 1); p = k & 1; isdup = (T == 0);
            if (s == 4) {
                int g = t / 3, kk = t - g * 3;
                const void* bnp = srcs.p[7];
                float ga = readw(bnp, (4 + g) * 128 + co, f32);
                float va = readw(bnp, (4 + g) * 128 + 96 + co, f32);
                float scl = ga * rsqrtf(va + BN_EPS);
                w = readw(srcs.p[4 + g], (kk * 32 + c) * 32 + co, f32) * scl;
            } else {
                w = readw(srcs.p[s == 1 ? 1 : 3], (t * 32 + c) * 32 + co, f32);
            }
        }
        uint16_t h = f2bf(w);
        Wf[i] = isdup ? h : (p == 0 ? f2bf(w - bf2f(h)) : (uint16_t)0);
    } else if (i < WF2_END + BN_CNT) {
        int j = i - WF2_END;
        bnf[j] = readw(srcs.p[7], j, f32);
    }
}

// x [N,16] -> interleaved hi/lo rows: uint32[c] = h_c | l_c<<16
__global__ void canon_x3(const void* __restrict__ xsrc,
                         uint32_t* __restrict__ xi, int total)
{
    int f32 = detect_f32_inline((const uint16_t*)xsrc);
    for (int i = blockIdx.x * blockDim.x + threadIdx.x; i < total;
         i += gridDim.x * blockDim.x) {
        float v = f32 ? ((const float*)xsrc)[i]
                      : bf2f(((const uint16_t*)xsrc)[i]);
        uint16_t h = f2bf(v);
        uint16_t l = f2bf(v - bf2f(h));
        xi[i] = (uint32_t)h | ((uint32_t)l << 16);
    }
}

// ---------------------------------------------------------------------------
// MFMA conv v3: interleaved rows, packed-dword epilogue stores.
// 256 thr = 4 waves, 128 voxels/block; wave: 32 vox x 32 co.
// ---------------------------------------------------------------------------
struct ConvJob {
    const uint16_t* feat;    // [N][2*CIN] shorts, interleaved h/l per channel
    const uint16_t* Wf;      // stage base
    const float*    bn;      // 128 floats gamma/beta/mean/var
    const uint32_t* addsrc;  // nullable [N][32] packed
    uint32_t*       out;     // [N][32] packed
    Taps9 taps;
};

#define MFMA_BF16(A, B, C) __builtin_amdgcn_mfma_f32_16x16x32_bf16(A, B, C, 0, 0, 0)

template<int CIN>
__launch_bounds__(256, 4)
__global__ void conv_mfma3(ConvJob j0, ConvJob j1,
                           const int* __restrict__ nbr, int N)
{
    __shared__ int sidx[9][128];
    const ConvJob J = (blockIdx.y == 1) ? j1 : j0;
    const int tid = threadIdx.x;
    const int n0  = blockIdx.x * 128;

    for (int i = tid; i < 9 * 128; i += 256) {
        int t = i >> 7, v = i & 127, n = n0 + v;
        sidx[t][v] = (n < N) ? nbr[(size_t)J.taps.t[t] * N + n] : -1;
    }
    __syncthreads();

    const int lane = tid & 63;
    const int m = lane & 15, q = lane >> 4;
    const int vt0 = (tid >> 6) * 32;
    const bf16x8 Z8 = {0, 0, 0, 0, 0, 0, 0, 0};

    f32x4 acc[2][2];
#pragma unroll
    for (int vt = 0; vt < 2; ++vt)
#pragma unroll
        for (int ot = 0; ot < 2; ++ot) acc[vt][ot] = {0.f, 0.f, 0.f, 0.f};

#pragma unroll
    for (int t = 0; t < 9; ++t) {
        if constexpr (CIN == 16) {
            const uint16_t* wb = J.Wf + t * 2048 + m * 32 + q * 8;
            bf16x8 B00 = *(const bf16x8*)(wb);               // T0 ot0
            bf16x8 B10 = *(const bf16x8*)(wb + 1024);        // T1 ot0
            bf16x8 B01 = *(const bf16x8*)(wb + 512);         // T0 ot1
            bf16x8 B11 = *(const bf16x8*)(wb + 1536);        // T1 ot1
#pragma unroll
            for (int vt = 0; vt < 2; ++vt) {
                int row = sidx[t][vt0 + vt * 16 + m];
                bf16x8 A = Z8;
                if (row >= 0)
                    A = *(const bf16x8*)(J.feat + (size_t)row * 32 + q * 8);
                acc[vt][0] = MFMA_BF16(A, B00, acc[vt][0]);
                acc[vt][0] = MFMA_BF16(A, B10, acc[vt][0]);
                acc[vt][1] = MFMA_BF16(A, B01, acc[vt][1]);
                acc[vt][1] = MFMA_BF16(A, B11, acc[vt][1]);
            }
        } else {
            const uint16_t* wb = J.Wf + t * 4096 + m * 32 + q * 8;
            bf16x8 B000 = *(const bf16x8*)(wb);              // G0 T0 ot0
            bf16x8 B010 = *(const bf16x8*)(wb + 1024);       // G0 T1 ot0
            bf16x8 B100 = *(const bf16x8*)(wb + 2048);       // G1 T0 ot0
            bf16x8 B110 = *(const bf16x8*)(wb + 3072);       // G1 T1 ot0
            bf16x8 B001 = *(const bf16x8*)(wb + 512);        // G0 T0 ot1
            bf16x8 B011 = *(const bf16x8*)(wb + 1536);
            bf16x8 B101 = *(const bf16x8*)(wb + 2560);
            bf16x8 B111 = *(const bf16x8*)(wb + 3584);
#pragma unroll
            for (int vt = 0; vt < 2; ++vt) {
                int row = sidx[t][vt0 + vt * 16 + m];
                bf16x8 A0 = Z8, A1 = Z8;
                if (row >= 0) {
                    const uint16_t* p = J.feat + (size_t)row * 64 + q * 8;
                    A0 = *(const bf16x8*)p;
                    A1 = *(const bf16x8*)(p + 32);
                }
                acc[vt][0] = MFMA_BF16(A0, B000, acc[vt][0]);
                acc[vt][0] = MFMA_BF16(A0, B010, acc[vt][0]);
                acc[vt][0] = MFMA_BF16(A1, B100, acc[vt][0]);
                acc[vt][0] = MFMA_BF16(A1, B110, acc[vt][0]);
                acc[vt][1] = MFMA_BF16(A0, B001, acc[vt][1]);
                acc[vt][1] = MFMA_BF16(A0, B011, acc[vt][1]);
                acc[vt][1] = MFMA_BF16(A1, B101, acc[vt][1]);
                acc[vt][1] = MFMA_BF16(A1, B111, acc[vt][1]);
            }
        }
    }

    // epilogue: C layout col=lane&15 (out-ch), row=quad*4+reg (voxel);
    // packed-dword stores: 16 lanes x 4B = fully covered 64B sectors.
#pragma unroll
    for (int ot = 0; ot < 2; ++ot) {
        int ch = ot * 16 + m;
        float ga = J.bn[ch], be = J.bn[32 + ch];
        float mu = J.bn[64 + ch], va = J.bn[96 + ch];
        float s = ga * rsqrtf(va + BN_EPS);
        float b = be - mu * s;
#pragma unroll
        for (int vt = 0; vt < 2; ++vt)
#pragma unroll
            for (int r = 0; r < 4; ++r) {
                int vox = n0 + vt0 + vt * 16 + q * 4 + r;
                if (vox >= N) continue;
                float xv = acc[vt][ot][r];
                xv = (xv >= 0.f) ? xv : SLOPE * xv;
                float o = xv * s + b;
                if (J.addsrc) {
                    uint32_t a = J.addsrc[(size_t)vox * 32 + ch];
                    o += bflo(a) + bfhi(a);
                }
                uint16_t h = f2bf(o);
                uint16_t l = f2bf(o - bf2f(h));
                J.out[(size_t)vox * 32 + ch] = (uint32_t)h | ((uint32_t)l << 16);
            }
    }
}

// ---------------------------------------------------------------------------
// MFMA recon v3: 7 unique taps (center shared by all 3 groups), BN scale
// pre-folded into Wf stage 4, sigmoid per group, gate-multiply by y.
// ---------------------------------------------------------------------------
__launch_bounds__(256, 3)
__global__ void recon_mfma3(const uint32_t* __restrict__ y32,
                            const uint16_t* __restrict__ xprobe,
                            const int* __restrict__ nbr,
                            const uint16_t* __restrict__ Wf4,
                            const float* __restrict__ bnf,
                            void* __restrict__ out_, int N)
{
    const int out_f32 = detect_f32_inline(xprobe);
    __shared__ int sidx[7][128];
    const int tid = threadIdx.x;
    const int n0  = blockIdx.x * 128;

    const int ut[7] = {4, 22, 10, 16, 12, 14, 13};
    for (int i = tid; i < 7 * 128; i += 256) {
        int t = i >> 7, v = i & 127, n = n0 + v;
        sidx[t][v] = (n < N) ? nbr[(size_t)ut[t] * N + n] : -1;
    }
    __syncthreads();

    const int lane = tid & 63;
    const int m = lane & 15, q = lane >> 4;
    const int vt0 = (tid >> 6) * 32;
    const bf16x8 Z8 = {0, 0, 0, 0, 0, 0, 0, 0};
    const uint16_t* y16 = (const uint16_t*)y32;

    f32x4 a[3][2][2];
#pragma unroll
    for (int g = 0; g < 3; ++g)
#pragma unroll
        for (int vt = 0; vt < 2; ++vt)
#pragma unroll
            for (int ot = 0; ot < 2; ++ot) a[g][vt][ot] = {0.f, 0.f, 0.f, 0.f};

    // edge taps: slot 2e+s2 (e=group), weight slice kk = 0 or 2
#pragma unroll
    for (int e = 0; e < 3; ++e)
#pragma unroll
        for (int s2 = 0; s2 < 2; ++s2) {
            int slot = 2 * e + s2;
            int t = e * 3 + s2 * 2;
            const uint16_t* wb = Wf4 + t * 4096 + m * 32 + q * 8;
            bf16x8 B000 = *(const bf16x8*)(wb);
            bf16x8 B010 = *(const bf16x8*)(wb + 1024);
            bf16x8 B100 = *(const bf16x8*)(wb + 2048);
            bf16x8 B110 = *(const bf16x8*)(wb + 3072);
            bf16x8 B001 = *(const bf16x8*)(wb + 512);
            bf16x8 B011 = *(const bf16x8*)(wb + 1536);
            bf16x8 B101 = *(const bf16x8*)(wb + 2560);
            bf16x8 B111 = *(const bf16x8*)(wb + 3584);
#pragma unroll
            for (int vt = 0; vt < 2; ++vt) {
                int row = sidx[slot][vt0 + vt * 16 + m];
                bf16x8 A0 = Z8, A1 = Z8;
                if (row >= 0) {
                    const uint16_t* p = y16 + (size_t)row * 64 + q * 8;
                    A0 = *(const bf16x8*)p;
                    A1 = *(const bf16x8*)(p + 32);
                }
                a[e][vt][0] = MFMA_BF16(A0, B000, a[e][vt][0]);
                a[e][vt][0] = MFMA_BF16(A0, B010, a[e][vt][0]);
                a[e][vt][0] = MFMA_BF16(A1, B100, a[e][vt][0]);
                a[e][vt][0] = MFMA_BF16(A1, B110, a[e][vt][0]);
                a[e][vt][1] = MFMA_BF16(A0, B001, a[e][vt][1]);
                a[e][vt][1] = MFMA_BF16(A0, B011, a[e][vt][1]);
                a[e][vt][1] = MFMA_BF16(A1, B101, a[e][vt][1]);
                a[e][vt][1] = MFMA_BF16(A1, B111, a[e][vt][1]);
            }
        }

    // center tap (slot 6, kk=1): gather once, apply to all 3 groups
#pragma unroll
    for (int vt = 0; vt < 2; ++vt) {
        int row = sidx[6][vt0 + vt * 16 + m];
        bf16x8 A0 = Z8, A1 = Z8;
        if (row >= 0) {
            const uint16_t* p = y16 + (size_t)row * 64 + q * 8;
            A0 = *(const bf16x8*)p;
            A1 = *(const bf16x8*)(p + 32);
        }
#pragma unroll
        for (int g = 0; g < 3; ++g) {
            const uint16_t* wb = Wf4 + (g * 3 + 1) * 4096 + m * 32 + q * 8;
            bf16x8 B000 = *(const bf16x8*)(wb);
            bf16x8 B010 = *(const bf16x8*)(wb + 1024);
            bf16x8 B100 = *(const bf16x8*)(wb + 2048);
            bf16x8 B110 = *(const bf16x8*)(wb + 3072);
            bf16x8 B001 = *(const bf16x8*)(wb + 512);
            bf16x8 B011 = *(const bf16x8*)(wb + 1536);
            bf16x8 B101 = *(const bf16x8*)(wb + 2560);
            bf16x8 B111 = *(const bf16x8*)(wb + 3584);
            a[g][vt][0] = MFMA_BF16(A0, B000, a[g][vt][0]);
            a[g][vt][0] = MFMA_BF16(A0, B010, a[g][vt][0]);
            a[g][vt][0] = MFMA_BF16(A1, B100, a[g][vt][0]);
            a[g][vt][0] = MFMA_BF16(A1, B110, a[g][vt][0]);
            a[g][vt][1] = MFMA_BF16(A0, B001, a[g][vt][1]);
            a[g][vt][1] = MFMA_BF16(A0, B011, a[g][vt][1]);
            a[g][vt][1] = MFMA_BF16(A1, B101, a[g][vt][1]);
            a[g][vt][1] = MFMA_BF16(A1, B111, a[g][vt][1]);
        }
    }

#pragma unroll
    for (int ot = 0; ot < 2; ++ot) {
        int ch = ot * 16 + m;
        float sh[3];
#pragma unroll
        for (int g = 0; g < 3; ++g) {
            const float* p = bnf + (size_t)(4 + g) * 128;
            float scl = p[ch] * rsqrtf(p[96 + ch] + BN_EPS);
            sh[g] = p[32 + ch] - p[64 + ch] * scl;
        }
#pragma unroll
        for (int vt = 0; vt < 2; ++vt)
#pragma unroll
            for (int r = 0; r < 4; ++r) {
                int vox = n0 + vt0 + vt * 16 + q * 4 + r;
                if (vox >= N) continue;
                float g0 = 1.f / (1.f + __expf(-(a[0][vt][ot][r] + sh[0])));
                float g1 = 1.f / (1.f + __expf(-(a[1][vt][ot][r] + sh[1])));
                float g2 = 1.f / (1.f + __expf(-(a[2][vt][ot][r] + sh[2])));
                uint32_t yw = y32[(size_t)vox * 32 + ch];
                float o = (g0 + g1 + g2) * (bflo(yw) + bfhi(yw));
                if (out_f32)
                    ((float*)out_)[(size_t)vox * 32 + ch] = o;
                else
                    ((uint16_t*)out_)[(size_t)vox * 32 + ch] = f2bf(o);
            }
    }
}

// ---------------------------------------------------------------------------
// Fallback VALU tier (round-4 proven) for tiny ws.
// ---------------------------------------------------------------------------
#define WC_W1   0
#define WC_W12  4608
#define WC_W2   13824
#define WC_W3   18432
#define WC_WR1  27648
#define WC_WR2  30720
#define WC_WR3  33792
#define WC_BNP  36864
#define WC_END  37760

__global__ void canon_weights_fb(WSrcs srcs, float* __restrict__ Wc,
                                 const uint16_t* __restrict__ xprobe)
{
    int f32 = detect_f32_inline(xprobe);
    const int offs[9] = {WC_W1, WC_W12, WC_W2, WC_W3, WC_WR1, WC_WR2,
                         WC_WR3, WC_BNP, WC_END};
    int i = blockIdx.x * 256 + threadIdx.x;
    if (i >= WC_END) return;
    int t = 0;
#pragma unroll
    for (int k = 1; k < 8; ++k) if (i >= offs[k]) t = k;
    Wc[i] = readw(srcs.p[t], i - offs[t], f32);
}

__global__ void canon_x_bf(const void* __restrict__ xsrc,
                           uint16_t* __restrict__ xc, int n)
{
    int f32 = detect_f32_inline((const uint16_t*)xsrc);
    for (int i = blockIdx.x * blockDim.x + threadIdx.x; i < n;
         i += gridDim.x * blockDim.x) {
        float v = f32 ? ((const float*)xsrc)[i]
                      : bf2f(((const uint16_t*)xsrc)[i]);
        xc[i] = f2bf(v);
    }
}

template<int CIN>
__launch_bounds__(256)
__global__ void conv_bn_lrelu_bf(const uint16_t* __restrict__ feat,
                                 const int* __restrict__ nbr,
                                 const float* __restrict__ Wg,
                                 const float* __restrict__ bnp,
                                 const uint16_t* __restrict__ addsrc,
                                 uint16_t* __restrict__ out,
                                 Taps9 taps, int N)
{
    __shared__ float Wl[9 * CIN * 32];
    __shared__ float fs[CIN][128];
    __shared__ int   sidx[128];
    __shared__ float bns[32], bnb[32];

    const int tid = threadIdx.x;
    const int n0  = blockIdx.x * 128;

    for (int i = tid; i < 9 * CIN * 32; i += 256) Wl[i] = Wg[i];
    if (tid < 32) {
        float g = bnp[tid], b = bnp[32 + tid];
        float mu = bnp[64 + tid], va = bnp[96 + tid];
        float s = g * rsqrtf(va + BN_EPS);
        bns[tid] = s; bnb[tid] = b - mu * s;
    }
    float acc[4][4];
#pragma unroll
    for (int v = 0; v < 4; ++v)
#pragma unroll
        for (int j = 0; j < 4; ++j) acc[v][j] = 0.f;

    const int vb = (tid >> 3) << 2, cg = (tid & 7) << 2;
    const int r = tid >> 1, h = tid & 1, j0 = h * (CIN / 2);

#pragma unroll 1
    for (int t = 0; t < 9; ++t) {
        __syncthreads();
        if (tid < 128) {
            int n = n0 + tid;
            sidx[tid] = (n < N) ? nbr[(size_t)taps.t[t] * N + n] : -1;
        }
        __syncthreads();
        int mm = sidx[r];
        if (mm >= 0) {
            const uint16_t* src = feat + (size_t)mm * CIN + j0;
#pragma unroll
            for (int qq = 0; qq < CIN / 2; qq += 8) {
                uint4 u = *reinterpret_cast<const uint4*>(src + qq);
                fs[j0 + qq + 0][r] = bflo(u.x); fs[j0 + qq + 1][r] = bfhi(u.x);
                fs[j0 + qq + 2][r] = bflo(u.y); fs[j0 + qq + 3][r] = bfhi(u.y);
                fs[j0 + qq + 4][r] = bflo(u.z); fs[j0 + qq + 5][r] = bfhi(u.z);
                fs[j0 + qq + 6][r] = bflo(u.w); fs[j0 + qq + 7][r] = bfhi(u.w);
            }
        } else {
#pragma unroll
            for (int qq = 0; qq < CIN / 2; ++qq) fs[j0 + qq][r] = 0.f;
        }
        __syncthreads();
        const float* wk = Wl + t * (CIN * 32) + cg;
#pragma unroll
        for (int ci = 0; ci < CIN; ++ci) {
            float4 f = *reinterpret_cast<const float4*>(&fs[ci][vb]);
            float4 w = *reinterpret_cast<const float4*>(wk + ci * 32);
            acc[0][0] += f.x * w.x; acc[0][1] += f.x * w.y; acc[0][2] += f.x * w.z; acc[0][3] += f.x * w.w;
            acc[1][0] += f.y * w.x; acc[1][1] += f.y * w.y; acc[1][2] += f.y * w.z; acc[1][3] += f.y * w.w;
            acc[2][0] += f.z * w.x; acc[2][1] += f.z * w.y; acc[2][2] += f.z * w.z; acc[2][3] += f.z * w.w;
            acc[3][0] += f.w * w.x; acc[3][1] += f.w * w.y; acc[3][2] += f.w * w.z; acc[3][3] += f.w * w.w;
        }
    }
#pragma unroll
    for (int v = 0; v < 4; ++v) {
        int n = n0 + vb + v;
        if (n >= N) continue;
        ushort4 st;
        uint16_t* ov = (uint16_t*)&st;
#pragma unroll
        for (int j = 0; j < 4; ++j) {
            float x = acc[v][j];
            x = (x >= 0.f) ? x : SLOPE * x;
            float o = x * bns[cg + j] + bnb[cg + j];
            if (addsrc) o += bf2f(addsrc[(size_t)n * 32 + cg + j]);
            ov[j] = f2bf(o);
        }
        *reinterpret_cast<ushort4*>(out + (size_t)n * 32 + cg) = st;
    }
}

__launch_bounds__(256, 4)
__global__ void recon_gate_bf(const uint16_t* __restrict__ y,
                              const int* __restrict__ nbr,
                              const float* __restrict__ Wc,
                              const uint16_t* __restrict__ xprobe,
                              void* __restrict__ out_, int N)
{
    __shared__ float Wl[3 * 32 * 32];
    __shared__ float fs[32][128];
    __shared__ int   sidx[128];
    __shared__ float scl[3][32], shf[3][32];

    const int tid = threadIdx.x;
    const int n0  = blockIdx.x * 128;
    const int out_f32 = detect_f32_inline(xprobe);

    if (tid < 96) {
        int g = tid >> 5, c = tid & 31;
        const float* p = Wc + WC_BNP + (size_t)(4 + g) * 128;
        float ga = p[c], be = p[32 + c], mu = p[64 + c], va = p[96 + c];
        float s = ga * rsqrtf(va + BN_EPS);
        scl[g][c] = s; shf[g][c] = be - mu * s;
    }
    const int vb = (tid >> 3) << 2, cg = (tid & 7) << 2;
    const int r = tid >> 1, h = tid & 1, j0 = h * 16;

    float gsum[4][4];
#pragma unroll
    for (int v = 0; v < 4; ++v)
#pragma unroll
        for (int j = 0; j < 4; ++j) gsum[v][j] = 0.f;

    const int taps[3][3] = {{4, 13, 22}, {10, 13, 16}, {12, 13, 14}};

#pragma unroll 1
    for (int g = 0; g < 3; ++g) {
        __syncthreads();
        {
            const float* src = Wc + WC_WR1 + g * 3072;
            for (int i = tid; i < 3072; i += 256)
                Wl[i] = src[i] * scl[g][i & 31];
        }
        float acc[4][4];
#pragma unroll
        for (int v = 0; v < 4; ++v)
#pragma unroll
            for (int j = 0; j < 4; ++j) acc[v][j] = 0.f;

#pragma unroll 1
        for (int k = 0; k < 3; ++k) {
            __syncthreads();
            if (tid < 128) {
                int n = n0 + tid;
                sidx[tid] = (n < N) ? nbr[(size_t)taps[g][k] * N + n] : -1;
            }
            __syncthreads();
            int mm = sidx[r];
            if (mm >= 0) {
                const uint16_t* src = y + (size_t)mm * 32 + j0;
#pragma unroll
                for (int qq = 0; qq < 16; qq += 8) {
                    uint4 u = *reinterpret_cast<const uint4*>(src + qq);
                    fs[j0 + qq + 0][r] = bflo(u.x); fs[j0 + qq + 1][r] = bfhi(u.x);
                    fs[j0 + qq + 2][r] = bflo(u.y); fs[j0 + qq + 3][r] = bfhi(u.y);
                    fs[j0 + qq + 4][r] = bflo(u.z); fs[j0 + qq + 5][r] = bfhi(u.z);
                    fs[j0 + qq + 6][r] = bflo(u.w); fs[j0 + qq + 7][r] = bfhi(u.w);
                }
            } else {
#pragma unroll
                for (int qq = 0; qq < 16; ++qq) fs[j0 + qq][r] = 0.f;
            }
            __syncthreads();
            const float* wk = Wl + k * (32 * 32) + cg;
#pragma unroll
            for (int ci = 0; ci < 32; ++ci) {
                float4 f = *reinterpret_cast<const float4*>(&fs[ci][vb]);
                float4 w = *reinterpret_cast<const float4*>(wk + ci * 32);
                acc[0][0] += f.x * w.x; acc[0][1] += f.x * w.y; acc[0][2] += f.x * w.z; acc[0][3] += f.x * w.w;
                acc[1][0] += f.y * w.x; acc[1][1] += f.y * w.y; acc[1][2] += f.y * w.z; acc[1][3] += f.y * w.w;
                acc[2][0] += f.z * w.x; acc[2][1] += f.z * w.y; acc[2][2] += f.z * w.z; acc[2][3] += f.z * w.w;
                acc[3][0] += f.w * w.x; acc[3][1] += f.w * w.y; acc[3][2] += f.w * w.z; acc[3][3] += f.w * w.w;
            }
        }
#pragma unroll
        for (int v = 0; v < 4; ++v)
#pragma unroll
            for (int j = 0; j < 4; ++j) {
                float x = acc[v][j] + shf[g][cg + j];
                gsum[v][j] += 1.f / (1.f + __expf(-x));
            }
    }
#pragma unroll
    for (int v = 0; v < 4; ++v) {
        int n = n0 + vb + v;
        if (n >= N) continue;
#pragma unroll
        for (int j = 0; j < 4; ++j) {
            float yv = bf2f(y[(size_t)n * 32 + cg + j]);
            float o = gsum[v][j] * yv;
            if (out_f32) ((float*)out_)[(size_t)n * 32 + cg + j] = o;
            else ((uint16_t*)out_)[(size_t)n * 32 + cg + j] = f2bf(o);
        }
    }
}

// ---------------------------------------------------------------------------
extern "C" void kernel_launch(void* const* d_in, const int* in_sizes, int n_in,
                              void* d_out, int out_size, void* d_ws, size_t ws_size,
                              hipStream_t stream)
{
    (void)n_in; (void)out_size;
    const void* x   = d_in[0];
    const int*  nbr = (const int*)d_in[1];
    const int N = in_sizes[0] / 16;
    const uint16_t* xprobe = (const uint16_t*)x;

    dim3 block(256);
    const int gx = (N + 127) / 128;
    Taps9 p133 = {{9, 10, 11, 12, 13, 14, 15, 16, 17}};
    Taps9 p313 = {{3, 4, 5, 12, 13, 14, 21, 22, 23}};
    WSrcs ws8 = {{ d_in[2], d_in[3], d_in[4], d_in[5],
                   d_in[6], d_in[7], d_in[8], d_in[9] }};

    // ws layout (MFMA tier): bnf [0,4096) | Wf [4096, 299008) | xi | A1 | A2 | B1
    float*    bnf = (float*)d_ws;
    uint16_t* Wf  = (uint16_t*)((char*)d_ws + 4096);
    uint32_t* xi  = (uint32_t*)((char*)d_ws + 299008);
    uint32_t* A1  = xi + (size_t)N * 16;
    uint32_t* A2  = A1 + (size_t)N * 32;
    uint32_t* B1  = A2 + (size_t)N * 32;
    const size_t need = 299008u + (size_t)N * 64 + 3u * (size_t)N * 128;

    if (ws_size >= need) {
        prep_all<<<(WF2_END + BN_CNT + 255) / 256, block, 0, stream>>>(xprobe, ws8, Wf, bnf);
        canon_x3<<<1024, block, 0, stream>>>(x, xi, N * 16);
        ConvJob c1  = {(const uint16_t*)xi, Wf + WF2_S0, bnf + 0 * 128, nullptr, A1, p133};
        ConvJob c2  = {(const uint16_t*)xi, Wf + WF2_S2, bnf + 2 * 128, nullptr, A2, p313};
        ConvJob c12 = {(const uint16_t*)A1, Wf + WF2_S1, bnf + 1 * 128, nullptr, B1, p313};
        ConvJob c3  = {(const uint16_t*)A2, Wf + WF2_S3, bnf + 3 * 128, B1,      A1, p133};
        conv_mfma3<16><<<dim3(gx, 2), block, 0, stream>>>(c1, c2, nbr, N);       // s1, r1
        conv_mfma3<32><<<dim3(gx, 1), block, 0, stream>>>(c12, c12, nbr, N);     // s
        conv_mfma3<32><<<dim3(gx, 1), block, 0, stream>>>(c3, c3, nbr, N);       // y = r + s
        recon_mfma3<<<gx, block, 0, stream>>>(A1, xprobe, nbr, Wf + WF2_S4, bnf, d_out, N);
    } else {
        // VALU fallback (all-bf16): Wc fp32 + xc + B in ws, A in d_out scratch
        float*    Wc = (float*)d_ws;
        uint16_t* xc = (uint16_t*)((char*)d_ws + (size_t)WC_END * 4 + 256);
        uint16_t* A  = (uint16_t*)d_out;
        uint16_t* B  = xc + (size_t)N * 16;
        const float* bn0 = Wc + WC_BNP + 0 * 128;
        const float* bn1 = Wc + WC_BNP + 1 * 128;
        const float* bn2 = Wc + WC_BNP + 2 * 128;
        const float* bn3 = Wc + WC_BNP + 3 * 128;
        canon_weights_fb<<<(WC_END + 255) / 256, block, 0, stream>>>(ws8, Wc, xprobe);
        canon_x_bf<<<1024, block, 0, stream>>>(x, xc, N * 16);
        conv_bn_lrelu_bf<16><<<gx, block, 0, stream>>>(xc, nbr, Wc + WC_W1,  bn0, nullptr, A, p133, N);
        conv_bn_lrelu_bf<32><<<gx, block, 0, stream>>>(A,  nbr, Wc + WC_W12, bn1, nullptr, B, p313, N);
        conv_bn_lrelu_bf<16><<<gx, block, 0, stream>>>(xc, nbr, Wc + WC_W2,  bn2, nullptr, A, p313, N);
        conv_bn_lrelu_bf<32><<<gx, block, 0, stream>>>(A,  nbr, Wc + WC_W3,  bn3, B,       B, p133, N);
        recon_gate_bf<<<gx, block, 0, stream>>>(B, nbr, Wc, xprobe, d_out, N);
    }
}

// Round 8
// 250.926 us; speedup vs baseline: 1.0211x; 1.0211x over previous
//
#include <hip/hip_runtime.h>
#include <cstdint>
#include <cstddef>

// Asymm_3d_spconv: ResContextBlock + ReconBlock over submanifold sparse convs.
// Round 8: rounds 6/7 convs were stuck at ~53us with nothing saturated and
// VGPR=32 -> serialized exposed gather latency (one outstanding scattered load
// per wave). This round: full register prefetch of ALL taps' A-fragments
// before any MFMA (CIN16 72 VGPR, CIN32 144, recon 112), per-lane direct nbr
// index loads (no LDS, no barrier), launch_bounds tuned so the arrays fit
// without spill. Layouts/numerics identical to round 7 (passing, absmax
// 0.0078): interleaved hi/lo rows (uint32 = h|l<<16), prepped B-frag weights,
// 3-term hi/lo product.

#define SLOPE 0.01f
#define BN_EPS 1e-5f

typedef __attribute__((ext_vector_type(8))) short bf16x8;
typedef __attribute__((ext_vector_type(4))) float f32x4;

__device__ __forceinline__ float bflo(uint32_t w) {
    union { uint32_t i; float f; } v; v.i = w << 16; return v.f;
}
__device__ __forceinline__ float bfhi(uint32_t w) {
    union { uint32_t i; float f; } v; v.i = w & 0xffff0000u; return v.f;
}
__device__ __forceinline__ float bf2f(uint16_t u) {
    union { uint32_t i; float f; } v; v.i = ((uint32_t)u) << 16; return v.f;
}
__device__ __forceinline__ uint16_t f2bf(float f) {  // RNE
    union { float f; uint32_t i; } v; v.f = f;
    uint32_t x = v.i;
    return (uint16_t)((x + 0x7fffu + ((x >> 16) & 1u)) >> 16);
}

struct Taps9 { int t[9]; };
struct WSrcs { const void* p[8]; };  // W1,W12,W2,W3,Wr1,Wr2,Wr3,bnp

// Wf (prepped weights) short offsets. CIN16 stages: [t9][T2][co32][k32];
// CIN32 stages: [t9][G2][T2][co32][k32].
#define WF2_S0  0
#define WF2_S1  18432
#define WF2_S2  55296
#define WF2_S3  73728
#define WF2_S4  110592
#define WF2_END 147456
#define BN_CNT  896

// Inline dtype probe: sample 128 fixed even shorts of x. fp32 payload's low
// mantissa halves decode to huge/NaN bf16 with p~0.5 each.
__device__ __forceinline__ int detect_f32_inline(const uint16_t* x16)
{
    int lane = threadIdx.x & 63;
    float a = bf2f(x16[4 * lane]);
    float b = bf2f(x16[4 * lane + 2]);
    int bad = (!(a > -16.f && a < 16.f)) || (!(b > -16.f && b < 16.f));
    return __ballot(bad) != 0ull;
}

__device__ __forceinline__ float readw(const void* p, int j, int f32)
{
    return f32 ? ((const float*)p)[j] : bf2f(((const uint16_t*)p)[j]);
}

// ---------------------------------------------------------------------------
// prep_all: Wf (all 5 stages, interleaved-K hi/lo B-frags; stage 4 folds the
// recon BN scale) + canonical fp32 bn table (7*128). (unchanged, round 7)
// ---------------------------------------------------------------------------
__global__ void prep_all(const uint16_t* __restrict__ xprobe, WSrcs srcs,
                         uint16_t* __restrict__ Wf, float* __restrict__ bnf)
{
    int f32 = detect_f32_inline(xprobe);
    int i = blockIdx.x * 256 + threadIdx.x;
    if (i < WF2_END) {
        int s, off;
        if      (i < WF2_S1) { s = 0; off = WF2_S0; }
        else if (i < WF2_S2) { s = 1; off = WF2_S1; }
        else if (i < WF2_S3) { s = 2; off = WF2_S2; }
        else if (i < WF2_S4) { s = 3; off = WF2_S3; }
        else                 { s = 4; off = WF2_S4; }
        int r = i - off;
        float w; int p, isdup;
        if (s == 0 || s == 2) {
            int t = r >> 11, T = (r >> 10) & 1;
            int co = (r >> 5) & 31, k = r & 31;
            int c = k >> 1; p = k & 1; isdup = (T == 0);
            w = readw(srcs.p[s == 0 ? 0 : 2], (t * 16 + c) * 32 + co, f32);
        } else {
            int t = r >> 12, r2 = r & 4095;
            int G = r2 >> 11, T = (r2 >> 10) & 1;
            int co = (r2 >> 5) & 31, k = r2 & 31;
            int c = G * 16 + (k >> 1); p = k & 1; isdup = (T == 0);
            if (s == 4) {
                int g = t / 3, kk = t - g * 3;
                const void* bnp = srcs.p[7];
                float ga = readw(bnp, (4 + g) * 128 + co, f32);
                float va = readw(bnp, (4 + g) * 128 + 96 + co, f32);
                float scl = ga * rsqrtf(va + BN_EPS);
                w = readw(srcs.p[4 + g], (kk * 32 + c) * 32 + co, f32) * scl;
            } else {
                w = readw(srcs.p[s == 1 ? 1 : 3], (t * 32 + c) * 32 + co, f32);
            }
        }
        uint16_t h = f2bf(w);
        Wf[i] = isdup ? h : (p == 0 ? f2bf(w - bf2f(h)) : (uint16_t)0);
    } else if (i < WF2_END + BN_CNT) {
        int j = i - WF2_END;
        bnf[j] = readw(srcs.p[7], j, f32);
    }
}

// x [N,16] -> interleaved hi/lo rows: uint32[c] = h_c | l_c<<16
__global__ void canon_x3(const void* __restrict__ xsrc,
                         uint32_t* __restrict__ xi, int total)
{
    int f32 = detect_f32_inline((const uint16_t*)xsrc);
    for (int i = blockIdx.x * blockDim.x + threadIdx.x; i < total;
         i += gridDim.x * blockDim.x) {
        float v = f32 ? ((const float*)xsrc)[i]
                      : bf2f(((const uint16_t*)xsrc)[i]);
        uint16_t h = f2bf(v);
        uint16_t l = f2bf(v - bf2f(h));
        xi[i] = (uint32_t)h | ((uint32_t)l << 16);
    }
}

// ---------------------------------------------------------------------------
// MFMA conv v4: full register prefetch of all 9 taps' A-frags, per-lane nbr
// loads, no LDS/barrier. 256 thr = 4 waves, 128 vox/block; wave: 32v x 32co.
// ---------------------------------------------------------------------------
struct ConvJob {
    const uint16_t* feat;    // [N][2*CIN] shorts, interleaved h/l per channel
    const uint16_t* Wf;      // stage base
    const float*    bn;      // 128 floats gamma/beta/mean/var
    const uint32_t* addsrc;  // nullable [N][32] packed
    uint32_t*       out;     // [N][32] packed
    Taps9 taps;
};

#define MFMA_BF16(A, B, C) __builtin_amdgcn_mfma_f32_16x16x32_bf16(A, B, C, 0, 0, 0)

template<int CIN>
__launch_bounds__(256, (CIN == 16 ? 3 : 2))
__global__ void conv_mfma4(ConvJob j0, ConvJob j1,
                           const int* __restrict__ nbr, int N)
{
    const ConvJob J = (blockIdx.y == 1) ? j1 : j0;
    const int tid = threadIdx.x;
    const int n0  = blockIdx.x * 128;
    const int lane = tid & 63;
    const int m = lane & 15, q = lane >> 4;
    const int vt0 = (tid >> 6) * 32;
    const bf16x8 Z8 = {0, 0, 0, 0, 0, 0, 0, 0};

    // batch 1: all neighbor indices (coalesced 16-int reads, q-broadcast)
    int rows[9][2];
#pragma unroll
    for (int t = 0; t < 9; ++t)
#pragma unroll
        for (int vt = 0; vt < 2; ++vt) {
            int n = n0 + vt0 + vt * 16 + m;
            rows[t][vt] = (n < N) ? nbr[(size_t)J.taps.t[t] * N + n] : -1;
        }

    f32x4 acc[2][2];
#pragma unroll
    for (int vt = 0; vt < 2; ++vt)
#pragma unroll
        for (int ot = 0; ot < 2; ++ot) acc[vt][ot] = {0.f, 0.f, 0.f, 0.f};

    if constexpr (CIN == 16) {
        // batch 2: all A-fragments (18 independent gathers in flight)
        bf16x8 A[9][2];
#pragma unroll
        for (int t = 0; t < 9; ++t)
#pragma unroll
            for (int vt = 0; vt < 2; ++vt) {
                int row = rows[t][vt];
                A[t][vt] = Z8;
                if (row >= 0)
                    A[t][vt] = *(const bf16x8*)(J.feat + (size_t)row * 32 + q * 8);
            }
#pragma unroll
        for (int t = 0; t < 9; ++t) {
            const uint16_t* wb = J.Wf + t * 2048 + m * 32 + q * 8;
            bf16x8 B00 = *(const bf16x8*)(wb);               // T0 ot0
            bf16x8 B10 = *(const bf16x8*)(wb + 1024);        // T1 ot0
            bf16x8 B01 = *(const bf16x8*)(wb + 512);         // T0 ot1
            bf16x8 B11 = *(const bf16x8*)(wb + 1536);        // T1 ot1
#pragma unroll
            for (int vt = 0; vt < 2; ++vt) {
                acc[vt][0] = MFMA_BF16(A[t][vt], B00, acc[vt][0]);
                acc[vt][0] = MFMA_BF16(A[t][vt], B10, acc[vt][0]);
                acc[vt][1] = MFMA_BF16(A[t][vt], B01, acc[vt][1]);
                acc[vt][1] = MFMA_BF16(A[t][vt], B11, acc[vt][1]);
            }
        }
    } else {
        bf16x8 A0[9][2], A1[9][2];
#pragma unroll
        for (int t = 0; t < 9; ++t)
#pragma unroll
            for (int vt = 0; vt < 2; ++vt) {
                int row = rows[t][vt];
                A0[t][vt] = Z8; A1[t][vt] = Z8;
                if (row >= 0) {
                    const uint16_t* p = J.feat + (size_t)row * 64 + q * 8;
                    A0[t][vt] = *(const bf16x8*)p;
                    A1[t][vt] = *(const bf16x8*)(p + 32);
                }
            }
#pragma unroll
        for (int t = 0; t < 9; ++t) {
            const uint16_t* wb = J.Wf + t * 4096 + m * 32 + q * 8;
            bf16x8 B000 = *(const bf16x8*)(wb);              // G0 T0 ot0
            bf16x8 B010 = *(const bf16x8*)(wb + 1024);       // G0 T1 ot0
            bf16x8 B100 = *(const bf16x8*)(wb + 2048);       // G1 T0 ot0
            bf16x8 B110 = *(const bf16x8*)(wb + 3072);       // G1 T1 ot0
            bf16x8 B001 = *(const bf16x8*)(wb + 512);        // ot1 variants
            bf16x8 B011 = *(const bf16x8*)(wb + 1536);
            bf16x8 B101 = *(const bf16x8*)(wb + 2560);
            bf16x8 B111 = *(const bf16x8*)(wb + 3584);
#pragma unroll
            for (int vt = 0; vt < 2; ++vt) {
                acc[vt][0] = MFMA_BF16(A0[t][vt], B000, acc[vt][0]);
                acc[vt][0] = MFMA_BF16(A0[t][vt], B010, acc[vt][0]);
                acc[vt][0] = MFMA_BF16(A1[t][vt], B100, acc[vt][0]);
                acc[vt][0] = MFMA_BF16(A1[t][vt], B110, acc[vt][0]);
                acc[vt][1] = MFMA_BF16(A0[t][vt], B001, acc[vt][1]);
                acc[vt][1] = MFMA_BF16(A0[t][vt], B011, acc[vt][1]);
                acc[vt][1] = MFMA_BF16(A1[t][vt], B101, acc[vt][1]);
                acc[vt][1] = MFMA_BF16(A1[t][vt], B111, acc[vt][1]);
            }
        }
    }

    // epilogue: C layout col=lane&15 (out-ch), row=quad*4+reg (voxel);
    // packed-dword stores (16 lanes x 4B = covered 64B chunks).
#pragma unroll
    for (int ot = 0; ot < 2; ++ot) {
        int ch = ot * 16 + m;
        float ga = J.bn[ch], be = J.bn[32 + ch];
        float mu = J.bn[64 + ch], va = J.bn[96 + ch];
        float s = ga * rsqrtf(va + BN_EPS);
        float b = be - mu * s;
#pragma unroll
        for (int vt = 0; vt < 2; ++vt)
#pragma unroll
            for (int r = 0; r < 4; ++r) {
                int vox = n0 + vt0 + vt * 16 + q * 4 + r;
                if (vox >= N) continue;
                float xv = acc[vt][ot][r];
                xv = (xv >= 0.f) ? xv : SLOPE * xv;
                float o = xv * s + b;
                if (J.addsrc) {
                    uint32_t a = J.addsrc[(size_t)vox * 32 + ch];
                    o += bflo(a) + bfhi(a);
                }
                uint16_t h = f2bf(o);
                uint16_t l = f2bf(o - bf2f(h));
                J.out[(size_t)vox * 32 + ch] = (uint32_t)h | ((uint32_t)l << 16);
            }
    }
}

// ---------------------------------------------------------------------------
// MFMA recon v4: 7 unique taps (center shared by all 3 groups), full A
// prefetch, per-lane nbr loads, no LDS/barrier.
// ---------------------------------------------------------------------------
__launch_bounds__(256, 2)
__global__ void recon_mfma4(const uint32_t* __restrict__ y32,
                            const uint16_t* __restrict__ xprobe,
                            const int* __restrict__ nbr,
                            const uint16_t* __restrict__ Wf4,
                            const float* __restrict__ bnf,
                            void* __restrict__ out_, int N)
{
    const int out_f32 = detect_f32_inline(xprobe);
    const int tid = threadIdx.x;
    const int n0  = blockIdx.x * 128;
    const int lane = tid & 63;
    const int m = lane & 15, q = lane >> 4;
    const int vt0 = (tid >> 6) * 32;
    const bf16x8 Z8 = {0, 0, 0, 0, 0, 0, 0, 0};
    const uint16_t* y16 = (const uint16_t*)y32;

    const int ut[7] = {4, 22, 10, 16, 12, 14, 13};
    int rows[7][2];
#pragma unroll
    for (int t = 0; t < 7; ++t)
#pragma unroll
        for (int vt = 0; vt < 2; ++vt) {
            int n = n0 + vt0 + vt * 16 + m;
            rows[t][vt] = (n < N) ? nbr[(size_t)ut[t] * N + n] : -1;
        }

    bf16x8 A0[7][2], A1[7][2];
#pragma unroll
    for (int t = 0; t < 7; ++t)
#pragma unroll
        for (int vt = 0; vt < 2; ++vt) {
            int row = rows[t][vt];
            A0[t][vt] = Z8; A1[t][vt] = Z8;
            if (row >= 0) {
                const uint16_t* p = y16 + (size_t)row * 64 + q * 8;
                A0[t][vt] = *(const bf16x8*)p;
                A1[t][vt] = *(const bf16x8*)(p + 32);
            }
        }

    f32x4 a[3][2][2];
#pragma unroll
    for (int g = 0; g < 3; ++g)
#pragma unroll
        for (int vt = 0; vt < 2; ++vt)
#pragma unroll
            for (int ot = 0; ot < 2; ++ot) a[g][vt][ot] = {0.f, 0.f, 0.f, 0.f};

    // edge taps: slot 2e+s2 (e=group), weight slice t = e*3 + s2*2
#pragma unroll
    for (int e = 0; e < 3; ++e)
#pragma unroll
        for (int s2 = 0; s2 < 2; ++s2) {
            int slot = 2 * e + s2;
            int t = e * 3 + s2 * 2;
            const uint16_t* wb = Wf4 + t * 4096 + m * 32 + q * 8;
            bf16x8 B000 = *(const bf16x8*)(wb);
            bf16x8 B010 = *(const bf16x8*)(wb + 1024);
            bf16x8 B100 = *(const bf16x8*)(wb + 2048);
            bf16x8 B110 = *(const bf16x8*)(wb + 3072);
            bf16x8 B001 = *(const bf16x8*)(wb + 512);
            bf16x8 B011 = *(const bf16x8*)(wb + 1536);
            bf16x8 B101 = *(const bf16x8*)(wb + 2560);
            bf16x8 B111 = *(const bf16x8*)(wb + 3584);
#pragma unroll
            for (int vt = 0; vt < 2; ++vt) {
                a[e][vt][0] = MFMA_BF16(A0[slot][vt], B000, a[e][vt][0]);
                a[e][vt][0] = MFMA_BF16(A0[slot][vt], B010, a[e][vt][0]);
                a[e][vt][0] = MFMA_BF16(A1[slot][vt], B100, a[e][vt][0]);
                a[e][vt][0] = MFMA_BF16(A1[slot][vt], B110, a[e][vt][0]);
                a[e][vt][1] = MFMA_BF16(A0[slot][vt], B001, a[e][vt][1]);
                a[e][vt][1] = MFMA_BF16(A0[slot][vt], B011, a[e][vt][1]);
                a[e][vt][1] = MFMA_BF16(A1[slot][vt], B101, a[e][vt][1]);
                a[e][vt][1] = MFMA_BF16(A1[slot][vt], B111, a[e][vt][1]);
            }
        }

    // center tap (slot 6, weight slice kk=1 of each group)
#pragma unroll
    for (int g = 0; g < 3; ++g) {
        const uint16_t* wb = Wf4 + (g * 3 + 1) * 4096 + m * 32 + q * 8;
        bf16x8 B000 = *(const bf16x8*)(wb);
        bf16x8 B010 = *(const bf16x8*)(wb + 1024);
        bf16x8 B100 = *(const bf16x8*)(wb + 2048);
        bf16x8 B110 = *(const bf16x8*)(wb + 3072);
        bf16x8 B001 = *(const bf16x8*)(wb + 512);
        bf16x8 B011 = *(const bf16x8*)(wb + 1536);
        bf16x8 B101 = *(const bf16x8*)(wb + 2560);
        bf16x8 B111 = *(const bf16x8*)(wb + 3584);
#pragma unroll
        for (int vt = 0; vt < 2; ++vt) {
            a[g][vt][0] = MFMA_BF16(A0[6][vt], B000, a[g][vt][0]);
            a[g][vt][0] = MFMA_BF16(A0[6][vt], B010, a[g][vt][0]);
            a[g][vt][0] = MFMA_BF16(A1[6][vt], B100, a[g][vt][0]);
            a[g][vt][0] = MFMA_BF16(A1[6][vt], B110, a[g][vt][0]);
            a[g][vt][1] = MFMA_BF16(A0[6][vt], B001, a[g][vt][1]);
            a[g][vt][1] = MFMA_BF16(A0[6][vt], B011, a[g][vt][1]);
            a[g][vt][1] = MFMA_BF16(A1[6][vt], B101, a[g][vt][1]);
            a[g][vt][1] = MFMA_BF16(A1[6][vt], B111, a[g][vt][1]);
        }
    }

#pragma unroll
    for (int ot = 0; ot < 2; ++ot) {
        int ch = ot * 16 + m;
        float sh[3];
#pragma unroll
        for (int g = 0; g < 3; ++g) {
            const float* p = bnf + (size_t)(4 + g) * 128;
            float scl = p[ch] * rsqrtf(p[96 + ch] + BN_EPS);
            sh[g] = p[32 + ch] - p[64 + ch] * scl;
        }
#pragma unroll
        for (int vt = 0; vt < 2; ++vt)
#pragma unroll
            for (int r = 0; r < 4; ++r) {
                int vox = n0 + vt0 + vt * 16 + q * 4 + r;
                if (vox >= N) continue;
                float g0 = 1.f / (1.f + __expf(-(a[0][vt][ot][r] + sh[0])));
                float g1 = 1.f / (1.f + __expf(-(a[1][vt][ot][r] + sh[1])));
                float g2 = 1.f / (1.f + __expf(-(a[2][vt][ot][r] + sh[2])));
                uint32_t yw = y32[(size_t)vox * 32 + ch];
                float o = (g0 + g1 + g2) * (bflo(yw) + bfhi(yw));
                if (out_f32)
                    ((float*)out_)[(size_t)vox * 32 + ch] = o;
                else
                    ((uint16_t*)out_)[(size_t)vox * 32 + ch] = f2bf(o);
            }
    }
}

// ---------------------------------------------------------------------------
// Fallback VALU tier (round-4 proven) for tiny ws.
// ---------------------------------------------------------------------------
#define WC_W1   0
#define WC_W12  4608
#define WC_W2   13824
#define WC_W3   18432
#define WC_WR1  27648
#define WC_WR2  30720
#define WC_WR3  33792
#define WC_BNP  36864
#define WC_END  37760

__global__ void canon_weights_fb(WSrcs srcs, float* __restrict__ Wc,
                                 const uint16_t* __restrict__ xprobe)
{
    int f32 = detect_f32_inline(xprobe);
    const int offs[9] = {WC_W1, WC_W12, WC_W2, WC_W3, WC_WR1, WC_WR2,
                         WC_WR3, WC_BNP, WC_END};
    int i = blockIdx.x * 256 + threadIdx.x;
    if (i >= WC_END) return;
    int t = 0;
#pragma unroll
    for (int k = 1; k < 8; ++k) if (i >= offs[k]) t = k;
    Wc[i] = readw(srcs.p[t], i - offs[t], f32);
}

__global__ void canon_x_bf(const void* __restrict__ xsrc,
                           uint16_t* __restrict__ xc, int n)
{
    int f32 = detect_f32_inline((const uint16_t*)xsrc);
    for (int i = blockIdx.x * blockDim.x + threadIdx.x; i < n;
         i += gridDim.x * blockDim.x) {
        float v = f32 ? ((const float*)xsrc)[i]
                      : bf2f(((const uint16_t*)xsrc)[i]);
        xc[i] = f2bf(v);
    }
}

template<int CIN>
__launch_bounds__(256)
__global__ void conv_bn_lrelu_bf(const uint16_t* __restrict__ feat,
                                 const int* __restrict__ nbr,
                                 const float* __restrict__ Wg,
                                 const float* __restrict__ bnp,
                                 const uint16_t* __restrict__ addsrc,
                                 uint16_t* __restrict__ out,
                                 Taps9 taps, int N)
{
    __shared__ float Wl[9 * CIN * 32];
    __shared__ float fs[CIN][128];
    __shared__ int   sidx[128];
    __shared__ float bns[32], bnb[32];

    const int tid = threadIdx.x;
    const int n0  = blockIdx.x * 128;

    for (int i = tid; i < 9 * CIN * 32; i += 256) Wl[i] = Wg[i];
    if (tid < 32) {
        float g = bnp[tid], b = bnp[32 + tid];
        float mu = bnp[64 + tid], va = bnp[96 + tid];
        float s = g * rsqrtf(va + BN_EPS);
        bns[tid] = s; bnb[tid] = b - mu * s;
    }
    float acc[4][4];
#pragma unroll
    for (int v = 0; v < 4; ++v)
#pragma unroll
        for (int j = 0; j < 4; ++j) acc[v][j] = 0.f;

    const int vb = (tid >> 3) << 2, cg = (tid & 7) << 2;
    const int r = tid >> 1, h = tid & 1, j0 = h * (CIN / 2);

#pragma unroll 1
    for (int t = 0; t < 9; ++t) {
        __syncthreads();
        if (tid < 128) {
            int n = n0 + tid;
            sidx[tid] = (n < N) ? nbr[(size_t)taps.t[t] * N + n] : -1;
        }
        __syncthreads();
        int mm = sidx[r];
        if (mm >= 0) {
            const uint16_t* src = feat + (size_t)mm * CIN + j0;
#pragma unroll
            for (int qq = 0; qq < CIN / 2; qq += 8) {
                uint4 u = *reinterpret_cast<const uint4*>(src + qq);
                fs[j0 + qq + 0][r] = bflo(u.x); fs[j0 + qq + 1][r] = bfhi(u.x);
                fs[j0 + qq + 2][r] = bflo(u.y); fs[j0 + qq + 3][r] = bfhi(u.y);
                fs[j0 + qq + 4][r] = bflo(u.z); fs[j0 + qq + 5][r] = bfhi(u.z);
                fs[j0 + qq + 6][r] = bflo(u.w); fs[j0 + qq + 7][r] = bfhi(u.w);
            }
        } else {
#pragma unroll
            for (int qq = 0; qq < CIN / 2; ++qq) fs[j0 + qq][r] = 0.f;
        }
        __syncthreads();
        const float* wk = Wl + t * (CIN * 32) + cg;
#pragma unroll
        for (int ci = 0; ci < CIN; ++ci) {
            float4 f = *reinterpret_cast<const float4*>(&fs[ci][vb]);
            float4 w = *reinterpret_cast<const float4*>(wk + ci * 32);
            acc[0][0] += f.x * w.x; acc[0][1] += f.x * w.y; acc[0][2] += f.x * w.z; acc[0][3] += f.x * w.w;
            acc[1][0] += f.y * w.x; acc[1][1] += f.y * w.y; acc[1][2] += f.y * w.z; acc[1][3] += f.y * w.w;
            acc[2][0] += f.z * w.x; acc[2][1] += f.z * w.y; acc[2][2] += f.z * w.z; acc[2][3] += f.z * w.w;
            acc[3][0] += f.w * w.x; acc[3][1] += f.w * w.y; acc[3][2] += f.w * w.z; acc[3][3] += f.w * w.w;
        }
    }
#pragma unroll
    for (int v = 0; v < 4; ++v) {
        int n = n0 + vb + v;
        if (n >= N) continue;
        ushort4 st;
        uint16_t* ov = (uint16_t*)&st;
#pragma unroll
        for (int j = 0; j < 4; ++j) {
            float x = acc[v][j];
            x = (x >= 0.f) ? x : SLOPE * x;
            float o = x * bns[cg + j] + bnb[cg + j];
            if (addsrc) o += bf2f(addsrc[(size_t)n * 32 + cg + j]);
            ov[j] = f2bf(o);
        }
        *reinterpret_cast<ushort4*>(out + (size_t)n * 32 + cg) = st;
    }
}

__launch_bounds__(256, 4)
__global__ void recon_gate_bf(const uint16_t* __restrict__ y,
                              const int* __restrict__ nbr,
                              const float* __restrict__ Wc,
                              const uint16_t* __restrict__ xprobe,
                              void* __restrict__ out_, int N)
{
    __shared__ float Wl[3 * 32 * 32];
    __shared__ float fs[32][128];
    __shared__ int   sidx[128];
    __shared__ float scl[3][32], shf[3][32];

    const int tid = threadIdx.x;
    const int n0  = blockIdx.x * 128;
    const int out_f32 = detect_f32_inline(xprobe);

    if (tid < 96) {
        int g = tid >> 5, c = tid & 31;
        const float* p = Wc + WC_BNP + (size_t)(4 + g) * 128;
        float ga = p[c], be = p[32 + c], mu = p[64 + c], va = p[96 + c];
        float s = ga * rsqrtf(va + BN_EPS);
        scl[g][c] = s; shf[g][c] = be - mu * s;
    }
    const int vb = (tid >> 3) << 2, cg = (tid & 7) << 2;
    const int r = tid >> 1, h = tid & 1, j0 = h * 16;

    float gsum[4][4];
#pragma unroll
    for (int v = 0; v < 4; ++v)
#pragma unroll
        for (int j = 0; j < 4; ++j) gsum[v][j] = 0.f;

    const int taps[3][3] = {{4, 13, 22}, {10, 13, 16}, {12, 13, 14}};

#pragma unroll 1
    for (int g = 0; g < 3; ++g) {
        __syncthreads();
        {
            const float* src = Wc + WC_WR1 + g * 3072;
            for (int i = tid; i < 3072; i += 256)
                Wl[i] = src[i] * scl[g][i & 31];
        }
        float acc[4][4];
#pragma unroll
        for (int v = 0; v < 4; ++v)
#pragma unroll
            for (int j = 0; j < 4; ++j) acc[v][j] = 0.f;

#pragma unroll 1
        for (int k = 0; k < 3; ++k) {
            __syncthreads();
            if (tid < 128) {
                int n = n0 + tid;
                sidx[tid] = (n < N) ? nbr[(size_t)taps[g][k] * N + n] : -1;
            }
            __syncthreads();
            int mm = sidx[r];
            if (mm >= 0) {
                const uint16_t* src = y + (size_t)mm * 32 + j0;
#pragma unroll
                for (int qq = 0; qq < 16; qq += 8) {
                    uint4 u = *reinterpret_cast<const uint4*>(src + qq);
                    fs[j0 + qq + 0][r] = bflo(u.x); fs[j0 + qq + 1][r] = bfhi(u.x);
                    fs[j0 + qq + 2][r] = bflo(u.y); fs[j0 + qq + 3][r] = bfhi(u.y);
                    fs[j0 + qq + 4][r] = bflo(u.z); fs[j0 + qq + 5][r] = bfhi(u.z);
                    fs[j0 + qq + 6][r] = bflo(u.w); fs[j0 + qq + 7][r] = bfhi(u.w);
                }
            } else {
#pragma unroll
                for (int qq = 0; qq < 16; ++qq) fs[j0 + qq][r] = 0.f;
            }
            __syncthreads();
            const float* wk = Wl + k * (32 * 32) + cg;
#pragma unroll
            for (int ci = 0; ci < 32; ++ci) {
                float4 f = *reinterpret_cast<const float4*>(&fs[ci][vb]);
                float4 w = *reinterpret_cast<const float4*>(wk + ci * 32);
                acc[0][0] += f.x * w.x; acc[0][1] += f.x * w.y; acc[0][2] += f.x * w.z; acc[0][3] += f.x * w.w;
                acc[1][0] += f.y * w.x; acc[1][1] += f.y * w.y; acc[1][2] += f.y * w.z; acc[1][3] += f.y * w.w;
                acc[2][0] += f.z * w.x; acc[2][1] += f.z * w.y; acc[2][2] += f.z * w.z; acc[2][3] += f.z * w.w;
                acc[3][0] += f.w * w.x; acc[3][1] += f.w * w.y; acc[3][2] += f.w * w.z; acc[3][3] += f.w * w.w;
            }
        }
#pragma unroll
        for (int v = 0; v < 4; ++v)
#pragma unroll
            for (int j = 0; j < 4; ++j) {
                float x = acc[v][j] + shf[g][cg + j];
                gsum[v][j] += 1.f / (1.f + __expf(-x));
            }
    }
#pragma unroll
    for (int v = 0; v < 4; ++v) {
        int n = n0 + vb + v;
        if (n >= N) continue;
#pragma unroll
        for (int j = 0; j < 4; ++j) {
            float yv = bf2f(y[(size_t)n * 32 + cg + j]);
            float o = gsum[v][j] * yv;
            if (out_f32) ((float*)out_)[(size_t)n * 32 + cg + j] = o;
            else ((uint16_t*)out_)[(size_t)n * 32 + cg + j] = f2bf(o);
        }
    }
}

// ---------------------------------------------------------------------------
extern "C" void kernel_launch(void* const* d_in, const int* in_sizes, int n_in,
                              void* d_out, int out_size, void* d_ws, size_t ws_size,
                              hipStream_t stream)
{
    (void)n_in; (void)out_size;
    const void* x   = d_in[0];
    const int*  nbr = (const int*)d_in[1];
    const int N = in_sizes[0] / 16;
    const uint16_t* xprobe = (const uint16_t*)x;

    dim3 block(256);
    const int gx = (N + 127) / 128;
    Taps9 p133 = {{9, 10, 11, 12, 13, 14, 15, 16, 17}};
    Taps9 p313 = {{3, 4, 5, 12, 13, 14, 21, 22, 23}};
    WSrcs ws8 = {{ d_in[2], d_in[3], d_in[4], d_in[5],
                   d_in[6], d_in[7], d_in[8], d_in[9] }};

    // ws layout (MFMA tier): bnf [0,4096) | Wf [4096, 299008) | xi | A1 | A2 | B1
    float*    bnf = (float*)d_ws;
    uint16_t* Wf  = (uint16_t*)((char*)d_ws + 4096);
    uint32_t* xi  = (uint32_t*)((char*)d_ws + 299008);
    uint32_t* A1  = xi + (size_t)N * 16;
    uint32_t* A2  = A1 + (size_t)N * 32;
    uint32_t* B1  = A2 + (size_t)N * 32;
    const size_t need = 299008u + (size_t)N * 64 + 3u * (size_t)N * 128;

    if (ws_size >= need) {
        prep_all<<<(WF2_END + BN_CNT + 255) / 256, block, 0, stream>>>(xprobe, ws8, Wf, bnf);
        canon_x3<<<1024, block, 0, stream>>>(x, xi, N * 16);
        ConvJob c1  = {(const uint16_t*)xi, Wf + WF2_S0, bnf + 0 * 128, nullptr, A1, p133};
        ConvJob c2  = {(const uint16_t*)xi, Wf + WF2_S2, bnf + 2 * 128, nullptr, A2, p313};
        ConvJob c12 = {(const uint16_t*)A1, Wf + WF2_S1, bnf + 1 * 128, nullptr, B1, p313};
        ConvJob c3  = {(const uint16_t*)A2, Wf + WF2_S3, bnf + 3 * 128, B1,      A1, p133};
        conv_mfma4<16><<<dim3(gx, 2), block, 0, stream>>>(c1, c2, nbr, N);       // s1, r1
        conv_mfma4<32><<<dim3(gx, 1), block, 0, stream>>>(c12, c12, nbr, N);     // s
        conv_mfma4<32><<<dim3(gx, 1), block, 0, stream>>>(c3, c3, nbr, N);       // y = r + s
        recon_mfma4<<<gx, block, 0, stream>>>(A1, xprobe, nbr, Wf + WF2_S4, bnf, d_out, N);
    } else {
        // VALU fallback (all-bf16): Wc fp32 + xc + B in ws, A in d_out scratch
        float*    Wc = (float*)d_ws;
        uint16_t* xc = (uint16_t*)((char*)d_ws + (size_t)WC_END * 4 + 256);
        uint16_t* A  = (uint16_t*)d_out;
        uint16_t* B  = xc + (size_t)N * 16;
        const float* bn0 = Wc + WC_BNP + 0 * 128;
        const float* bn1 = Wc + WC_BNP + 1 * 128;
        const float* bn2 = Wc + WC_BNP + 2 * 128;
        const float* bn3 = Wc + WC_BNP + 3 * 128;
        canon_weights_fb<<<(WC_END + 255) / 256, block, 0, stream>>>(ws8, Wc, xprobe);
        canon_x_bf<<<1024, block, 0, stream>>>(x, xc, N * 16);
        conv_bn_lrelu_bf<16><<<gx, block, 0, stream>>>(xc, nbr, Wc + WC_W1,  bn0, nullptr, A, p133, N);
        conv_bn_lrelu_bf<32><<<gx, block, 0, stream>>>(A,  nbr, Wc + WC_W12, bn1, nullptr, B, p313, N);
        conv_bn_lrelu_bf<16><<<gx, block, 0, stream>>>(xc, nbr, Wc + WC_W2,  bn2, nullptr, A, p313, N);
        conv_bn_lrelu_bf<32><<<gx, block, 0, stream>>>(A,  nbr, Wc + WC_W3,  bn3, B,       B, p133, N);
        recon_gate_bf<<<gx, block, 0, stream>>>(B, nbr, Wc, xprobe, d_out, N);
    }
}

// Round 9
// 194.647 us; speedup vs baseline: 1.3163x; 1.2891x over previous
//
#include <hip/hip_runtime.h>
#include <cstdint>
#include <cstddef>

// Asymm_3d_spconv: ResContextBlock + ReconBlock over submanifold sparse convs.
// Round 9: round-8's register prefetch was defeated by the compiler (recon
// VGPR=80 << the ~160 needed -> loads sunk back to uses -> serialized gather
// latency). Two changes:
//  1) 2-term hi-A product: intermediates stored bf16-hi ONLY (64B rows);
//     weights stay hi/lo split (Ah*Bh + Ah*Bl = Ah*w, fp32-precision weights,
//     bf16 activations). Halves gather volume, MFMA count, and prefetch VGPR.
//     x keeps exact interleaved hi/lo (K=32 via [wh,wh]/[wl,0] dup weights).
//  2) sched_barrier(0) fences: (idx loads) | (A loads) | (MFMA+epilogue),
//     launch_bounds(256,3) so ~140 VGPR of live frags fit without sinking.
// Conv kernel is now structurally identical for CIN16/CIN32 (same 64B row
// stride; only prepped weight content differs).

#define SLOPE 0.01f
#define BN_EPS 1e-5f

typedef __attribute__((ext_vector_type(8))) short bf16x8;
typedef __attribute__((ext_vector_type(4))) float f32x4;

__device__ __forceinline__ float bflo(uint32_t w) {
    union { uint32_t i; float f; } v; v.i = w << 16; return v.f;
}
__device__ __forceinline__ float bfhi(uint32_t w) {
    union { uint32_t i; float f; } v; v.i = w & 0xffff0000u; return v.f;
}
__device__ __forceinline__ float bf2f(uint16_t u) {
    union { uint32_t i; float f; } v; v.i = ((uint32_t)u) << 16; return v.f;
}
__device__ __forceinline__ uint16_t f2bf(float f) {  // RNE
    union { float f; uint32_t i; } v; v.f = f;
    uint32_t x = v.i;
    return (uint16_t)((x + 0x7fffu + ((x >> 16) & 1u)) >> 16);
}

struct Taps9 { int t[9]; };
struct WSrcs { const void* p[8]; };  // W1,W12,W2,W3,Wr1,Wr2,Wr3,bnp

// Wf: 5 stages x [t9][T2][co32][k32] shorts, 18432 each.
// CIN16 stages (0,2): k-space is interleaved (c=k>>1, part=k&1);
//   T0 = [wh,wh] dup, T1 = [wl,0].
// CIN32 stages (1,3,4): k = channel; T0 = wh, T1 = wl. Stage 4 folds BN scale.
#define WFS     18432
#define WF_END  (5 * WFS)
#define BN_CNT  896

__device__ __forceinline__ int detect_f32_inline(const uint16_t* x16)
{
    int lane = threadIdx.x & 63;
    float a = bf2f(x16[4 * lane]);
    float b = bf2f(x16[4 * lane + 2]);
    int bad = (!(a > -16.f && a < 16.f)) || (!(b > -16.f && b < 16.f));
    return __ballot(bad) != 0ull;
}

__device__ __forceinline__ float readw(const void* p, int j, int f32)
{
    return f32 ? ((const float*)p)[j] : bf2f(((const uint16_t*)p)[j]);
}

// ---------------------------------------------------------------------------
__global__ void prep_all(const uint16_t* __restrict__ xprobe, WSrcs srcs,
                         uint16_t* __restrict__ Wf, float* __restrict__ bnf)
{
    int f32 = detect_f32_inline(xprobe);
    int i = blockIdx.x * 256 + threadIdx.x;
    if (i < WF_END) {
        int s = i / WFS, r = i - s * WFS;
        int t = r >> 11, T = (r >> 10) & 1;
        int co = (r >> 5) & 31, k = r & 31;
        uint16_t outv;
        if (s == 0 || s == 2) {
            int c = k >> 1, p = k & 1;
            float w = readw(srcs.p[s == 0 ? 0 : 2], (t * 16 + c) * 32 + co, f32);
            uint16_t h = f2bf(w);
            outv = (T == 0) ? h : (p == 0 ? f2bf(w - bf2f(h)) : (uint16_t)0);
        } else {
            float w;
            if (s == 4) {
                int g = t / 3, kk = t - g * 3;
                const void* bnp = srcs.p[7];
                float ga = readw(bnp, (4 + g) * 128 + co, f32);
                float va = readw(bnp, (4 + g) * 128 + 96 + co, f32);
                float scl = ga * rsqrtf(va + BN_EPS);
                w = readw(srcs.p[4 + g], (kk * 32 + k) * 32 + co, f32) * scl;
            } else {
                w = readw(srcs.p[s == 1 ? 1 : 3], (t * 32 + k) * 32 + co, f32);
            }
            uint16_t h = f2bf(w);
            outv = (T == 0) ? h : f2bf(w - bf2f(h));
        }
        Wf[i] = outv;
    } else if (i < WF_END + BN_CNT) {
        bnf[i - WF_END] = readw(srcs.p[7], i - WF_END, f32);
    }
}

// x [N,16] -> interleaved hi/lo rows (exact): short[row*32 + 2c]=h, [+1]=l
__global__ void canon_x3(const void* __restrict__ xsrc,
                         uint32_t* __restrict__ xi, int total)
{
    int f32 = detect_f32_inline((const uint16_t*)xsrc);
    for (int i = blockIdx.x * blockDim.x + threadIdx.x; i < total;
         i += gridDim.x * blockDim.x) {
        float v = f32 ? ((const float*)xsrc)[i]
                      : bf2f(((const uint16_t*)xsrc)[i]);
        int row = i >> 4, c = i & 15;
        uint16_t h = f2bf(v);
        uint16_t l = f2bf(v - bf2f(h));
        xi[(size_t)row * 16 + c] = (uint32_t)h | ((uint32_t)l << 16);
    }
}

// ---------------------------------------------------------------------------
// conv v5: 64B feat rows (x: interleaved hi/lo of 16ch; intermediates: hi of
// 32ch). 256 thr = 4 waves, 128 vox/block; wave: 32 vox x 32 co. Batched
// index loads | batched A loads | MFMA, separated by sched_barrier(0).
// ---------------------------------------------------------------------------
struct ConvJob {
    const uint16_t* feat;    // [N][32] shorts (64B rows)
    const uint16_t* Wf;      // stage base [9][2][32][32]
    const float*    bn;      // 128 floats gamma/beta/mean/var
    const uint16_t* addsrc;  // nullable [N][32] bf16-hi
    uint16_t*       out;     // [N][32] bf16-hi
    Taps9 taps;
};

#define MFMA_BF16(A, B, C) __builtin_amdgcn_mfma_f32_16x16x32_bf16(A, B, C, 0, 0, 0)

__launch_bounds__(256, 3)
__global__ void conv_mfma5(ConvJob j0, ConvJob j1,
                           const int* __restrict__ nbr, int N)
{
    const ConvJob J = (blockIdx.y == 1) ? j1 : j0;
    const int tid = threadIdx.x;
    const int n0  = blockIdx.x * 128;
    const int lane = tid & 63;
    const int m = lane & 15, q = lane >> 4;
    const int vt0 = (tid >> 6) * 32;
    const bf16x8 Z8 = {0, 0, 0, 0, 0, 0, 0, 0};

    int rows[9][2];
#pragma unroll
    for (int t = 0; t < 9; ++t)
#pragma unroll
        for (int vt = 0; vt < 2; ++vt) {
            int n = n0 + vt0 + vt * 16 + m;
            rows[t][vt] = (n < N) ? nbr[(size_t)J.taps.t[t] * N + n] : -1;
        }
    __builtin_amdgcn_sched_barrier(0);

    bf16x8 A[9][2];
#pragma unroll
    for (int t = 0; t < 9; ++t)
#pragma unroll
        for (int vt = 0; vt < 2; ++vt) {
            int row = rows[t][vt];
            A[t][vt] = Z8;
            if (row >= 0)
                A[t][vt] = *(const bf16x8*)(J.feat + (size_t)row * 32 + q * 8);
        }
    __builtin_amdgcn_sched_barrier(0);

    f32x4 acc[2][2];
#pragma unroll
    for (int vt = 0; vt < 2; ++vt)
#pragma unroll
        for (int ot = 0; ot < 2; ++ot) acc[vt][ot] = {0.f, 0.f, 0.f, 0.f};

#pragma unroll
    for (int t = 0; t < 9; ++t) {
        const uint16_t* wb = J.Wf + t * 2048 + m * 32 + q * 8;
        bf16x8 B00 = *(const bf16x8*)(wb);               // T0 ot0
        bf16x8 B10 = *(const bf16x8*)(wb + 1024);        // T1 ot0
        bf16x8 B01 = *(const bf16x8*)(wb + 512);         // T0 ot1
        bf16x8 B11 = *(const bf16x8*)(wb + 1536);        // T1 ot1
#pragma unroll
        for (int vt = 0; vt < 2; ++vt) {
            acc[vt][0] = MFMA_BF16(A[t][vt], B00, acc[vt][0]);
            acc[vt][0] = MFMA_BF16(A[t][vt], B10, acc[vt][0]);
            acc[vt][1] = MFMA_BF16(A[t][vt], B01, acc[vt][1]);
            acc[vt][1] = MFMA_BF16(A[t][vt], B11, acc[vt][1]);
        }
    }

    // epilogue: C layout col=lane&15 (out-ch), row=quad*4+reg (voxel)
#pragma unroll
    for (int ot = 0; ot < 2; ++ot) {
        int ch = ot * 16 + m;
        float ga = J.bn[ch], be = J.bn[32 + ch];
        float mu = J.bn[64 + ch], va = J.bn[96 + ch];
        float s = ga * rsqrtf(va + BN_EPS);
        float b = be - mu * s;
#pragma unroll
        for (int vt = 0; vt < 2; ++vt)
#pragma unroll
            for (int r = 0; r < 4; ++r) {
                int vox = n0 + vt0 + vt * 16 + q * 4 + r;
                if (vox >= N) continue;
                float xv = acc[vt][ot][r];
                xv = (xv >= 0.f) ? xv : SLOPE * xv;
                float o = xv * s + b;
                if (J.addsrc) o += bf2f(J.addsrc[(size_t)vox * 32 + ch]);
                J.out[(size_t)vox * 32 + ch] = f2bf(o);
            }
    }
}

// ---------------------------------------------------------------------------
// recon v5: 7 unique taps on y (bf16-hi rows), 2-term product, BN scale in
// Wf stage 4, sigmoid per group, gate-multiply by y.
// ---------------------------------------------------------------------------
__launch_bounds__(256, 3)
__global__ void recon_mfma5(const uint16_t* __restrict__ y16,
                            const uint16_t* __restrict__ xprobe,
                            const int* __restrict__ nbr,
                            const uint16_t* __restrict__ Wf4,
                            const float* __restrict__ bnf,
                            void* __restrict__ out_, int N)
{
    const int out_f32 = detect_f32_inline(xprobe);
    const int tid = threadIdx.x;
    const int n0  = blockIdx.x * 128;
    const int lane = tid & 63;
    const int m = lane & 15, q = lane >> 4;
    const int vt0 = (tid >> 6) * 32;
    const bf16x8 Z8 = {0, 0, 0, 0, 0, 0, 0, 0};

    const int ut[7] = {4, 22, 10, 16, 12, 14, 13};
    int rows[7][2];
#pragma unroll
    for (int t = 0; t < 7; ++t)
#pragma unroll
        for (int vt = 0; vt < 2; ++vt) {
            int n = n0 + vt0 + vt * 16 + m;
            rows[t][vt] = (n < N) ? nbr[(size_t)ut[t] * N + n] : -1;
        }
    __builtin_amdgcn_sched_barrier(0);

    bf16x8 A[7][2];
#pragma unroll
    for (int t = 0; t < 7; ++t)
#pragma unroll
        for (int vt = 0; vt < 2; ++vt) {
            int row = rows[t][vt];
            A[t][vt] = Z8;
            if (row >= 0)
                A[t][vt] = *(const bf16x8*)(y16 + (size_t)row * 32 + q * 8);
        }
    __builtin_amdgcn_sched_barrier(0);

    f32x4 a[3][2][2];
#pragma unroll
    for (int g = 0; g < 3; ++g)
#pragma unroll
        for (int vt = 0; vt < 2; ++vt)
#pragma unroll
            for (int ot = 0; ot < 2; ++ot) a[g][vt][ot] = {0.f, 0.f, 0.f, 0.f};

    // edge taps: slot 2e+s2, weight slice t = e*3 + s2*2
#pragma unroll
    for (int e = 0; e < 3; ++e)
#pragma unroll
        for (int s2 = 0; s2 < 2; ++s2) {
            int slot = 2 * e + s2;
            int t = e * 3 + s2 * 2;
            const uint16_t* wb = Wf4 + t * 2048 + m * 32 + q * 8;
            bf16x8 B00 = *(const bf16x8*)(wb);
            bf16x8 B10 = *(const bf16x8*)(wb + 1024);
            bf16x8 B01 = *(const bf16x8*)(wb + 512);
            bf16x8 B11 = *(const bf16x8*)(wb + 1536);
#pragma unroll
            for (int vt = 0; vt < 2; ++vt) {
                a[e][vt][0] = MFMA_BF16(A[slot][vt], B00, a[e][vt][0]);
                a[e][vt][0] = MFMA_BF16(A[slot][vt], B10, a[e][vt][0]);
                a[e][vt][1] = MFMA_BF16(A[slot][vt], B01, a[e][vt][1]);
                a[e][vt][1] = MFMA_BF16(A[slot][vt], B11, a[e][vt][1]);
            }
        }
    // center tap (slot 6, weight slice kk=1 of each group)
#pragma unroll
    for (int g = 0; g < 3; ++g) {
        const uint16_t* wb = Wf4 + (g * 3 + 1) * 2048 + m * 32 + q * 8;
        bf16x8 B00 = *(const bf16x8*)(wb);
        bf16x8 B10 = *(const bf16x8*)(wb + 1024);
        bf16x8 B01 = *(const bf16x8*)(wb + 512);
        bf16x8 B11 = *(const bf16x8*)(wb + 1536);
#pragma unroll
        for (int vt = 0; vt < 2; ++vt) {
            a[g][vt][0] = MFMA_BF16(A[6][vt], B00, a[g][vt][0]);
            a[g][vt][0] = MFMA_BF16(A[6][vt], B10, a[g][vt][0]);
            a[g][vt][1] = MFMA_BF16(A[6][vt], B01, a[g][vt][1]);
            a[g][vt][1] = MFMA_BF16(A[6][vt], B11, a[g][vt][1]);
        }
    }

#pragma unroll
    for (int ot = 0; ot < 2; ++ot) {
        int ch = ot * 16 + m;
        float sh[3];
#pragma unroll
        for (int g = 0; g < 3; ++g) {
            const float* p = bnf + (size_t)(4 + g) * 128;
            float scl = p[ch] * rsqrtf(p[96 + ch] + BN_EPS);
            sh[g] = p[32 + ch] - p[64 + ch] * scl;
        }
#pragma unroll
        for (int vt = 0; vt < 2; ++vt)
#pragma unroll
            for (int r = 0; r < 4; ++r) {
                int vox = n0 + vt0 + vt * 16 + q * 4 + r;
                if (vox >= N) continue;
                float g0 = 1.f / (1.f + __expf(-(a[0][vt][ot][r] + sh[0])));
                float g1 = 1.f / (1.f + __expf(-(a[1][vt][ot][r] + sh[1])));
                float g2 = 1.f / (1.f + __expf(-(a[2][vt][ot][r] + sh[2])));
                float o = (g0 + g1 + g2) * bf2f(y16[(size_t)vox * 32 + ch]);
                if (out_f32)
                    ((float*)out_)[(size_t)vox * 32 + ch] = o;
                else
                    ((uint16_t*)out_)[(size_t)vox * 32 + ch] = f2bf(o);
            }
    }
}

// ---------------------------------------------------------------------------
// Fallback VALU tier (round-4 proven) for tiny ws.
// ---------------------------------------------------------------------------
#define WC_W1   0
#define WC_W12  4608
#define WC_W2   13824
#define WC_W3   18432
#define WC_WR1  27648
#define WC_WR2  30720
#define WC_WR3  33792
#define WC_BNP  36864
#define WC_END  37760

__global__ void canon_weights_fb(WSrcs srcs, float* __restrict__ Wc,
                                 const uint16_t* __restrict__ xprobe)
{
    int f32 = detect_f32_inline(xprobe);
    const int offs[9] = {WC_W1, WC_W12, WC_W2, WC_W3, WC_WR1, WC_WR2,
                         WC_WR3, WC_BNP, WC_END};
    int i = blockIdx.x * 256 + threadIdx.x;
    if (i >= WC_END) return;
    int t = 0;
#pragma unroll
    for (int k = 1; k < 8; ++k) if (i >= offs[k]) t = k;
    Wc[i] = readw(srcs.p[t], i - offs[t], f32);
}

__global__ void canon_x_bf(const void* __restrict__ xsrc,
                           uint16_t* __restrict__ xc, int n)
{
    int f32 = detect_f32_inline((const uint16_t*)xsrc);
    for (int i = blockIdx.x * blockDim.x + threadIdx.x; i < n;
         i += gridDim.x * blockDim.x) {
        float v = f32 ? ((const float*)xsrc)[i]
                      : bf2f(((const uint16_t*)xsrc)[i]);
        xc[i] = f2bf(v);
    }
}

template<int CIN>
__launch_bounds__(256)
__global__ void conv_bn_lrelu_bf(const uint16_t* __restrict__ feat,
                                 const int* __restrict__ nbr,
                                 const float* __restrict__ Wg,
                                 const float* __restrict__ bnp,
                                 const uint16_t* __restrict__ addsrc,
                                 uint16_t* __restrict__ out,
                                 Taps9 taps, int N)
{
    __shared__ float Wl[9 * CIN * 32];
    __shared__ float fs[CIN][128];
    __shared__ int   sidx[128];
    __shared__ float bns[32], bnb[32];

    const int tid = threadIdx.x;
    const int n0  = blockIdx.x * 128;

    for (int i = tid; i < 9 * CIN * 32; i += 256) Wl[i] = Wg[i];
    if (tid < 32) {
        float g = bnp[tid], b = bnp[32 + tid];
        float mu = bnp[64 + tid], va = bnp[96 + tid];
        float s = g * rsqrtf(va + BN_EPS);
        bns[tid] = s; bnb[tid] = b - mu * s;
    }
    float acc[4][4];
#pragma unroll
    for (int v = 0; v < 4; ++v)
#pragma unroll
        for (int j = 0; j < 4; ++j) acc[v][j] = 0.f;

    const int vb = (tid >> 3) << 2, cg = (tid & 7) << 2;
    const int r = tid >> 1, h = tid & 1, j0 = h * (CIN / 2);

#pragma unroll 1
    for (int t = 0; t < 9; ++t) {
        __syncthreads();
        if (tid < 128) {
            int n = n0 + tid;
            sidx[tid] = (n < N) ? nbr[(size_t)taps.t[t] * N + n] : -1;
        }
        __syncthreads();
        int mm = sidx[r];
        if (mm >= 0) {
            const uint16_t* src = feat + (size_t)mm * CIN + j0;
#pragma unroll
            for (int qq = 0; qq < CIN / 2; qq += 8) {
                uint4 u = *reinterpret_cast<const uint4*>(src + qq);
                fs[j0 + qq + 0][r] = bflo(u.x); fs[j0 + qq + 1][r] = bfhi(u.x);
                fs[j0 + qq + 2][r] = bflo(u.y); fs[j0 + qq + 3][r] = bfhi(u.y);
                fs[j0 + qq + 4][r] = bflo(u.z); fs[j0 + qq + 5][r] = bfhi(u.z);
                fs[j0 + qq + 6][r] = bflo(u.w); fs[j0 + qq + 7][r] = bfhi(u.w);
            }
        } else {
#pragma unroll
            for (int qq = 0; qq < CIN / 2; ++qq) fs[j0 + qq][r] = 0.f;
        }
        __syncthreads();
        const float* wk = Wl + t * (CIN * 32) + cg;
#pragma unroll
        for (int ci = 0; ci < CIN; ++ci) {
            float4 f = *reinterpret_cast<const float4*>(&fs[ci][vb]);
            float4 w = *reinterpret_cast<const float4*>(wk + ci * 32);
            acc[0][0] += f.x * w.x; acc[0][1] += f.x * w.y; acc[0][2] += f.x * w.z; acc[0][3] += f.x * w.w;
            acc[1][0] += f.y * w.x; acc[1][1] += f.y * w.y; acc[1][2] += f.y * w.z; acc[1][3] += f.y * w.w;
            acc[2][0] += f.z * w.x; acc[2][1] += f.z * w.y; acc[2][2] += f.z * w.z; acc[2][3] += f.z * w.w;
            acc[3][0] += f.w * w.x; acc[3][1] += f.w * w.y; acc[3][2] += f.w * w.z; acc[3][3] += f.w * w.w;
        }
    }
#pragma unroll
    for (int v = 0; v < 4; ++v) {
        int n = n0 + vb + v;
        if (n >= N) continue;
        ushort4 st;
        uint16_t* ov = (uint16_t*)&st;
#pragma unroll
        for (int j = 0; j < 4; ++j) {
            float x = acc[v][j];
            x = (x >= 0.f) ? x : SLOPE * x;
            float o = x * bns[cg + j] + bnb[cg + j];
            if (addsrc) o += bf2f(addsrc[(size_t)n * 32 + cg + j]);
            ov[j] = f2bf(o);
        }
        *reinterpret_cast<ushort4*>(out + (size_t)n * 32 + cg) = st;
    }
}

__launch_bounds__(256, 4)
__global__ void recon_gate_bf(const uint16_t* __restrict__ y,
                              const int* __restrict__ nbr,
                              const float* __restrict__ Wc,
                              const uint16_t* __restrict__ xprobe,
                              void* __restrict__ out_, int N)
{
    __shared__ float Wl[3 * 32 * 32];
    __shared__ float fs[32][128];
    __shared__ int   sidx[128];
    __shared__ float scl[3][32], shf[3][32];

    const int tid = threadIdx.x;
    const int n0  = blockIdx.x * 128;
    const int out_f32 = detect_f32_inline(xprobe);

    if (tid < 96) {
        int g = tid >> 5, c = tid & 31;
        const float* p = Wc + WC_BNP + (size_t)(4 + g) * 128;
        float ga = p[c], be = p[32 + c], mu = p[64 + c], va = p[96 + c];
        float s = ga * rsqrtf(va + BN_EPS);
        scl[g][c] = s; shf[g][c] = be - mu * s;
    }
    const int vb = (tid >> 3) << 2, cg = (tid & 7) << 2;
    const int r = tid >> 1, h = tid & 1, j0 = h * 16;

    float gsum[4][4];
#pragma unroll
    for (int v = 0; v < 4; ++v)
#pragma unroll
        for (int j = 0; j < 4; ++j) gsum[v][j] = 0.f;

    const int taps[3][3] = {{4, 13, 22}, {10, 13, 16}, {12, 13, 14}};

#pragma unroll 1
    for (int g = 0; g < 3; ++g) {
        __syncthreads();
        {
            const float* src = Wc + WC_WR1 + g * 3072;
            for (int i = tid; i < 3072; i += 256)
                Wl[i] = src[i] * scl[g][i & 31];
        }
        float acc[4][4];
#pragma unroll
        for (int v = 0; v < 4; ++v)
#pragma unroll
            for (int j = 0; j < 4; ++j) acc[v][j] = 0.f;

#pragma unroll 1
        for (int k = 0; k < 3; ++k) {
            __syncthreads();
            if (tid < 128) {
                int n = n0 + tid;
                sidx[tid] = (n < N) ? nbr[(size_t)taps[g][k] * N + n] : -1;
            }
            __syncthreads();
            int mm = sidx[r];
            if (mm >= 0) {
                const uint16_t* src = y + (size_t)mm * 32 + j0;
#pragma unroll
                for (int qq = 0; qq < 16; qq += 8) {
                    uint4 u = *reinterpret_cast<const uint4*>(src + qq);
                    fs[j0 + qq + 0][r] = bflo(u.x); fs[j0 + qq + 1][r] = bfhi(u.x);
                    fs[j0 + qq + 2][r] = bflo(u.y); fs[j0 + qq + 3][r] = bfhi(u.y);
                    fs[j0 + qq + 4][r] = bflo(u.z); fs[j0 + qq + 5][r] = bfhi(u.z);
                    fs[j0 + qq + 6][r] = bflo(u.w); fs[j0 + qq + 7][r] = bfhi(u.w);
                }
            } else {
#pragma unroll
                for (int qq = 0; qq < 16; ++qq) fs[j0 + qq][r] = 0.f;
            }
            __syncthreads();
            const float* wk = Wl + k * (32 * 32) + cg;
#pragma unroll
            for (int ci = 0; ci < 32; ++ci) {
                float4 f = *reinterpret_cast<const float4*>(&fs[ci][vb]);
                float4 w = *reinterpret_cast<const float4*>(wk + ci * 32);
                acc[0][0] += f.x * w.x; acc[0][1] += f.x * w.y; acc[0][2] += f.x * w.z; acc[0][3] += f.x * w.w;
                acc[1][0] += f.y * w.x; acc[1][1] += f.y * w.y; acc[1][2] += f.y * w.z; acc[1][3] += f.y * w.w;
                acc[2][0] += f.z * w.x; acc[2][1] += f.z * w.y; acc[2][2] += f.z * w.z; acc[2][3] += f.z * w.w;
                acc[3][0] += f.w * w.x; acc[3][1] += f.w * w.y; acc[3][2] += f.w * w.z; acc[3][3] += f.w * w.w;
            }
        }
#pragma unroll
        for (int v = 0; v < 4; ++v)
#pragma unroll
            for (int j = 0; j < 4; ++j) {
                float x = acc[v][j] + shf[g][cg + j];
                gsum[v][j] += 1.f / (1.f + __expf(-x));
            }
    }
#pragma unroll
    for (int v = 0; v < 4; ++v) {
        int n = n0 + vb + v;
        if (n >= N) continue;
#pragma unroll
        for (int j = 0; j < 4; ++j) {
            float yv = bf2f(y[(size_t)n * 32 + cg + j]);
            float o = gsum[v][j] * yv;
            if (out_f32) ((float*)out_)[(size_t)n * 32 + cg + j] = o;
            else ((uint16_t*)out_)[(size_t)n * 32 + cg + j] = f2bf(o);
        }
    }
}

// ---------------------------------------------------------------------------
extern "C" void kernel_launch(void* const* d_in, const int* in_sizes, int n_in,
                              void* d_out, int out_size, void* d_ws, size_t ws_size,
                              hipStream_t stream)
{
    (void)n_in; (void)out_size;
    const void* x   = d_in[0];
    const int*  nbr = (const int*)d_in[1];
    const int N = in_sizes[0] / 16;
    const uint16_t* xprobe = (const uint16_t*)x;

    dim3 block(256);
    const int gx = (N + 127) / 128;
    Taps9 p133 = {{9, 10, 11, 12, 13, 14, 15, 16, 17}};
    Taps9 p313 = {{3, 4, 5, 12, 13, 14, 21, 22, 23}};
    WSrcs ws8 = {{ d_in[2], d_in[3], d_in[4], d_in[5],
                   d_in[6], d_in[7], d_in[8], d_in[9] }};

    // ws layout (MFMA tier): bnf [0,4096) | Wf [4096, 4096+184320) | xi|A1|A2|B1
    float*    bnf = (float*)d_ws;
    uint16_t* Wf  = (uint16_t*)((char*)d_ws + 4096);
    const size_t base2 = 4096u + (size_t)WF_END * 2;   // 188416
    uint16_t* xi  = (uint16_t*)((char*)d_ws + base2);  // [N][32] interleaved
    uint16_t* A1  = xi + (size_t)N * 32;               // [N][32] bf16-hi
    uint16_t* A2  = A1 + (size_t)N * 32;
    uint16_t* B1  = A2 + (size_t)N * 32;
    const size_t need = base2 + 4u * (size_t)N * 64;

    if (ws_size >= need) {
        prep_all<<<(WF_END + BN_CNT + 255) / 256, block, 0, stream>>>(xprobe, ws8, Wf, bnf);
        canon_x3<<<1024, block, 0, stream>>>(x, (uint32_t*)xi, N * 16);
        ConvJob c1  = {xi, Wf + 0 * WFS, bnf + 0 * 128, nullptr, A1, p133};
        ConvJob c2  = {xi, Wf + 2 * WFS, bnf + 2 * 128, nullptr, A2, p313};
        ConvJob c12 = {A1, Wf + 1 * WFS, bnf + 1 * 128, nullptr, B1, p313};
        ConvJob c3  = {A2, Wf + 3 * WFS, bnf + 3 * 128, B1,      A1, p133};
        conv_mfma5<<<dim3(gx, 2), block, 0, stream>>>(c1, c2, nbr, N);   // s1, r1
        conv_mfma5<<<dim3(gx, 1), block, 0, stream>>>(c12, c12, nbr, N); // s
        conv_mfma5<<<dim3(gx, 1), block, 0, stream>>>(c3, c3, nbr, N);   // y = r+s
        recon_mfma5<<<gx, block, 0, stream>>>(A1, xprobe, nbr, Wf + 4 * WFS, bnf, d_out, N);
    } else {
        // VALU fallback (all-bf16)
        float*    Wc = (float*)d_ws;
        uint16_t* xc = (uint16_t*)((char*)d_ws + (size_t)WC_END * 4 + 256);
        uint16_t* A  = (uint16_t*)d_out;
        uint16_t* B  = xc + (size_t)N * 16;
        const float* bn0 = Wc + WC_BNP + 0 * 128;
        const float* bn1 = Wc + WC_BNP + 1 * 128;
        const float* bn2 = Wc + WC_BNP + 2 * 128;
        const float* bn3 = Wc + WC_BNP + 3 * 128;
        canon_weights_fb<<<(WC_END + 255) / 256, block, 0, stream>>>(ws8, Wc, xprobe);
        canon_x_bf<<<1024, block, 0, stream>>>(x, xc, N * 16);
        conv_bn_lrelu_bf<16><<<gx, block, 0, stream>>>(xc, nbr, Wc + WC_W1,  bn0, nullptr, A, p133, N);
        conv_bn_lrelu_bf<32><<<gx, block, 0, stream>>>(A,  nbr, Wc + WC_W12, bn1, nullptr, B, p313, N);
        conv_bn_lrelu_bf<16><<<gx, block, 0, stream>>>(xc, nbr, Wc + WC_W2,  bn2, nullptr, A, p313, N);
        conv_bn_lrelu_bf<32><<<gx, block, 0, stream>>>(A,  nbr, Wc + WC_W3,  bn3, B,       B, p133, N);
        recon_gate_bf<<<gx, block, 0, stream>>>(B, nbr, Wc, xprobe, d_out, N);
    }
}